// Round 1
// baseline (38.315 us; speedup 1.0000x reference)
//
#include <hip/hip_runtime.h>

// Problem constants (from reference): DIM=4096, WIDTH=4, POOL=512, BATCH=256, SEQ=16
constexpr int DIM   = 4096;
constexpr int WIDTH = 4;
constexpr int POOL  = 512;
constexpr int BATCH = 256;
constexpr int SEQ   = 16;

// ---------------------------------------------------------------------------
// Kernel 1: copy conv_state -> out_state (all POOL rows). Grid-stride float4.
// ---------------------------------------------------------------------------
__global__ __launch_bounds__(256) void copy_state_kernel(
    const float4* __restrict__ src, float4* __restrict__ dst, int n4)
{
    int i = blockIdx.x * blockDim.x + threadIdx.x;
    const int stride = gridDim.x * blockDim.x;
    for (; i < n4; i += stride) dst[i] = src[i];
}

// ---------------------------------------------------------------------------
// Kernel 2: per (b, d4) column: sliding-window conv + SiLU, then write the
// new state (last WIDTH-1 x rows, still live in window registers) to
// out_state[idx[b]]. Must run AFTER copy_state_kernel (same stream => ordered).
// ---------------------------------------------------------------------------
__global__ __launch_bounds__(256) void conv_silu_kernel(
    const float* __restrict__ x,           // [BATCH, SEQ, DIM]
    const float* __restrict__ conv_state,  // [POOL, WIDTH-1, DIM]
    const float* __restrict__ weight,      // [WIDTH, DIM]
    const float* __restrict__ bias,        // [DIM]
    const int*   __restrict__ idxs,        // [BATCH]
    float*       __restrict__ out,         // [BATCH, SEQ, DIM]
    float*       __restrict__ out_state)   // [POOL, WIDTH-1, DIM]
{
    const int b = blockIdx.y;
    const int d = (blockIdx.x * 256 + threadIdx.x) * 4;  // float4 column
    const int idx = idxs[b];

    // Per-column weights and bias (broadcast across s)
    float4 w[WIDTH];
#pragma unroll
    for (int k = 0; k < WIDTH; ++k)
        w[k] = *reinterpret_cast<const float4*>(weight + (size_t)k * DIM + d);
    const float4 bs = *reinterpret_cast<const float4*>(bias + d);

    // Window registers: win[t] = x_new[s + t]
    float4 win[WIDTH];
#pragma unroll
    for (int t = 0; t < WIDTH - 1; ++t)
        win[t] = *reinterpret_cast<const float4*>(
            conv_state + ((size_t)idx * (WIDTH - 1) + t) * DIM + d);

    const float* xb = x   + (size_t)b * SEQ * DIM + d;
    float*       ob = out + (size_t)b * SEQ * DIM + d;

    for (int s = 0; s < SEQ; ++s) {
        win[WIDTH - 1] = *reinterpret_cast<const float4*>(xb + (size_t)s * DIM);

        float4 acc = bs;
#pragma unroll
        for (int k = 0; k < WIDTH; ++k) {
            acc.x += win[k].x * w[k].x;
            acc.y += win[k].y * w[k].y;
            acc.z += win[k].z * w[k].z;
            acc.w += win[k].w * w[k].w;
        }
        // SiLU: v * sigmoid(v) = v / (1 + exp(-v))
        acc.x = acc.x / (1.0f + expf(-acc.x));
        acc.y = acc.y / (1.0f + expf(-acc.y));
        acc.z = acc.z / (1.0f + expf(-acc.z));
        acc.w = acc.w / (1.0f + expf(-acc.w));

        *reinterpret_cast<float4*>(ob + (size_t)s * DIM) = acc;

        // slide window
#pragma unroll
        for (int t = 0; t < WIDTH - 1; ++t) win[t] = win[t + 1];
    }

    // After the loop, win[0..2] = x[b, SEQ-3 .. SEQ-1, d..d+3] = new state.
#pragma unroll
    for (int t = 0; t < WIDTH - 1; ++t)
        *reinterpret_cast<float4*>(
            out_state + ((size_t)idx * (WIDTH - 1) + t) * DIM + d) = win[t];
}

// ---------------------------------------------------------------------------
extern "C" void kernel_launch(void* const* d_in, const int* in_sizes, int n_in,
                              void* d_out, int out_size, void* d_ws, size_t ws_size,
                              hipStream_t stream)
{
    const float* x          = (const float*)d_in[0];
    const float* conv_state = (const float*)d_in[1];
    const float* weight     = (const float*)d_in[2];
    const float* bias       = (const float*)d_in[3];
    const int*   idxs       = (const int*)  d_in[4];

    float* out       = (float*)d_out;                               // [BATCH,SEQ,DIM]
    float* out_state = out + (size_t)BATCH * SEQ * DIM;             // [POOL,WIDTH-1,DIM]

    // 1) copy conv_state into out_state (covers rows not selected by indices)
    const int n4 = POOL * (WIDTH - 1) * DIM / 4;  // float4 count
    copy_state_kernel<<<2048, 256, 0, stream>>>(
        (const float4*)conv_state, (float4*)out_state, n4);

    // 2) conv + SiLU + fused state scatter (ordered after copy on same stream)
    dim3 grid(DIM / (4 * 256), BATCH);  // (4, 256)
    conv_silu_kernel<<<grid, 256, 0, stream>>>(
        x, conv_state, weight, bias, idxs, out, out_state);
}

// Round 2
// 33.490 us; speedup vs baseline: 1.1441x; 1.1441x over previous
//
#include <hip/hip_runtime.h>

// Problem constants: DIM=4096, WIDTH=4, POOL=512, BATCH=256, SEQ=16
constexpr int DIM   = 4096;
constexpr int WIDTH = 4;
constexpr int POOL  = 512;
constexpr int BATCH = 256;
constexpr int SEQ   = 16;

constexpr int D4_CHUNKS    = DIM / (4 * 256);          // 4 column-chunks per batch row
constexpr int CONV_BLOCKS  = D4_CHUNKS * BATCH;        // 1024
constexpr int TOTAL_BLOCKS = CONV_BLOCKS + POOL;       // 1536

// ---------------------------------------------------------------------------
// Fused kernel.
//   Blocks [0, CONV_BLOCKS):  sliding-window conv + SiLU for one (b, d-chunk),
//     then write the new state (last WIDTH-1 x rows, live in registers) to
//     out_state[idx[b]].
//   Blocks [CONV_BLOCKS, +POOL): copy conv_state row -> out_state row, but
//     ONLY if the row is NOT in idxs (those rows are owned by the conv path).
//   Write sets are disjoint => no inter-block ordering required.
// ---------------------------------------------------------------------------
__global__ __launch_bounds__(256) void fused_conv_update_kernel(
    const float* __restrict__ x,           // [BATCH, SEQ, DIM]
    const float* __restrict__ conv_state,  // [POOL, WIDTH-1, DIM]
    const float* __restrict__ weight,      // [WIDTH, DIM]
    const float* __restrict__ bias,        // [DIM]
    const int*   __restrict__ idxs,        // [BATCH]
    float*       __restrict__ out,         // [BATCH, SEQ, DIM]
    float*       __restrict__ out_state)   // [POOL, WIDTH-1, DIM]
{
    const int blk = blockIdx.x;

    if (blk < CONV_BLOCKS) {
        // ----------------- conv + SiLU + fused state scatter -----------------
        const int b     = blk >> 2;              // blk / D4_CHUNKS
        const int chunk = blk & (D4_CHUNKS - 1);
        const int d     = (chunk * 256 + threadIdx.x) * 4;
        const int idx   = idxs[b];

        float4 w[WIDTH];
#pragma unroll
        for (int k = 0; k < WIDTH; ++k)
            w[k] = *reinterpret_cast<const float4*>(weight + (size_t)k * DIM + d);
        const float4 bs = *reinterpret_cast<const float4*>(bias + d);

        float4 win[WIDTH];
#pragma unroll
        for (int t = 0; t < WIDTH - 1; ++t)
            win[t] = *reinterpret_cast<const float4*>(
                conv_state + ((size_t)idx * (WIDTH - 1) + t) * DIM + d);

        const float* xb = x   + (size_t)b * SEQ * DIM + d;
        float*       ob = out + (size_t)b * SEQ * DIM + d;

#pragma unroll
        for (int s = 0; s < SEQ; ++s) {
            win[WIDTH - 1] = *reinterpret_cast<const float4*>(xb + (size_t)s * DIM);

            float4 acc = bs;
#pragma unroll
            for (int k = 0; k < WIDTH; ++k) {
                acc.x += win[k].x * w[k].x;
                acc.y += win[k].y * w[k].y;
                acc.z += win[k].z * w[k].z;
                acc.w += win[k].w * w[k].w;
            }
            // SiLU: v / (1 + exp(-v))
            acc.x = acc.x / (1.0f + expf(-acc.x));
            acc.y = acc.y / (1.0f + expf(-acc.y));
            acc.z = acc.z / (1.0f + expf(-acc.z));
            acc.w = acc.w / (1.0f + expf(-acc.w));

            *reinterpret_cast<float4*>(ob + (size_t)s * DIM) = acc;

#pragma unroll
            for (int t = 0; t < WIDTH - 1; ++t) win[t] = win[t + 1];
        }

        // win[0..2] = x[b, SEQ-3 .. SEQ-1, d..d+3] = new state for row idx.
#pragma unroll
        for (int t = 0; t < WIDTH - 1; ++t)
            *reinterpret_cast<float4*>(
                out_state + ((size_t)idx * (WIDTH - 1) + t) * DIM + d) = win[t];
    } else {
        // ----------------- selective state-row copy -----------------
        const int row = blk - CONV_BLOCKS;

        // Block-uniform membership test: skip rows owned by the conv path.
        __shared__ int skip;
        if (threadIdx.x == 0) skip = 0;
        __syncthreads();
        if (idxs[threadIdx.x] == row) skip = 1;   // BATCH == blockDim.x == 256
        __syncthreads();
        if (skip) return;

        const float4* src = reinterpret_cast<const float4*>(
            conv_state + (size_t)row * (WIDTH - 1) * DIM);
        float4* dst = reinterpret_cast<float4*>(
            out_state + (size_t)row * (WIDTH - 1) * DIM);

        constexpr int ROW_F4 = (WIDTH - 1) * DIM / 4;   // 3072 float4 per row
#pragma unroll
        for (int i = threadIdx.x; i < ROW_F4; i += 256)
            dst[i] = src[i];
    }
}

// ---------------------------------------------------------------------------
extern "C" void kernel_launch(void* const* d_in, const int* in_sizes, int n_in,
                              void* d_out, int out_size, void* d_ws, size_t ws_size,
                              hipStream_t stream)
{
    const float* x          = (const float*)d_in[0];
    const float* conv_state = (const float*)d_in[1];
    const float* weight     = (const float*)d_in[2];
    const float* bias       = (const float*)d_in[3];
    const int*   idxs       = (const int*)  d_in[4];

    float* out       = (float*)d_out;                    // [BATCH,SEQ,DIM]
    float* out_state = out + (size_t)BATCH * SEQ * DIM;  // [POOL,WIDTH-1,DIM]

    fused_conv_update_kernel<<<TOTAL_BLOCKS, 256, 0, stream>>>(
        x, conv_state, weight, bias, idxs, out, out_state);
}